// Round 1
// baseline (787.728 us; speedup 1.0000x reference)
//
#include <hip/hip_runtime.h>
#include <math.h>

// ---------------------------------------------------------------------------
// EncoderLayer: LN1 -> MHA -> +res -> LN2 -> top2-MoE -> +res
// B=4 S=1024 D=1024 H=16 DK=64 E=8 DFF=2048
//
// Precision strategy:
//  - Pre-router path (LN1, QKV, attention, Wo, LN2, router) must be
//    fp32-faithful (top_k selection is discontinuous). Implemented with
//    split-f16 MFMA: a = ah + al*2^-11 (al stored prescaled x2048; weights
//    prescaled x256) -> 3 MFMAs, dual accumulators, exact pow2 merge.
//    Effective relative error ~2^-22 (fp32-class), denorm-proof.
//  - MoE FFN (post-selection) is plain f16 MFMA, only routed tokens computed.
// ---------------------------------------------------------------------------

typedef _Float16 f16;
typedef _Float16 f16x8 __attribute__((ext_vector_type(8)));
typedef _Float16 f16x4 __attribute__((ext_vector_type(4)));
typedef float f32x4 __attribute__((ext_vector_type(4)));

#define LO_SCALE 2048.0f
#define INV_LO   (1.0f/2048.0f)
#define INV_W    (1.0f/256.0f)
#define INV_WLO  (1.0f/(256.0f*2048.0f))

#define MFMA16(a, b, c) __builtin_amdgcn_mfma_f32_16x16x32_f16(a, b, c, 0, 0, 0)

__device__ __forceinline__ void gl_lds16(const void* g, void* l) {
  __builtin_amdgcn_global_load_lds(
      (const __attribute__((address_space(1))) void*)g,
      (__attribute__((address_space(3))) void*)l, 16, 0, 0);
}

// ---------------- weight conversion ----------------
// fp32 -> split f16 with weight prescale x256 (hi) and x2048 (lo)
__global__ __launch_bounds__(256) void cvt_w_kernel(
    const float* __restrict__ in, f16* __restrict__ oh, f16* __restrict__ ol, int n4) {
  const int i = blockIdx.x * 256 + threadIdx.x;
  if (i >= n4) return;
  const float4 v = ((const float4*)in)[i];
  f16x4 hv, lv;
  float a;
  a = v.x * 256.0f; hv[0] = (f16)a; lv[0] = (f16)((a - (float)hv[0]) * LO_SCALE);
  a = v.y * 256.0f; hv[1] = (f16)a; lv[1] = (f16)((a - (float)hv[1]) * LO_SCALE);
  a = v.z * 256.0f; hv[2] = (f16)a; lv[2] = (f16)((a - (float)hv[2]) * LO_SCALE);
  a = v.w * 256.0f; hv[3] = (f16)a; lv[3] = (f16)((a - (float)hv[3]) * LO_SCALE);
  ((f16x4*)oh)[i] = hv;
  ((f16x4*)ol)[i] = lv;
}

// fp32 -> plain f16 (MoE weights)
__global__ __launch_bounds__(256) void cvt_h_kernel(
    const float* __restrict__ in, f16* __restrict__ out, int n4) {
  const int i = blockIdx.x * 256 + threadIdx.x;
  if (i >= n4) return;
  const float4 v = ((const float4*)in)[i];
  f16x4 ov = {(f16)v.x, (f16)v.y, (f16)v.z, (f16)v.w};
  ((f16x4*)out)[i] = ov;
}

// ---------------- layernorm ----------------
__global__ __launch_bounds__(256) void ln_kernel(
    const float* __restrict__ x, const float* __restrict__ g, const float* __restrict__ bb,
    f16* __restrict__ oh, f16* __restrict__ ol,     // split output (for split GEMM A)
    f16* __restrict__ o1,                            // plain f16 output (for MoE A)
    float* __restrict__ of)                          // fp32 output (for router)
{
  const int t = blockIdx.x, tid = threadIdx.x;
  const float4 v = ((const float4*)(x + (long)t * 1024))[tid];
  float s  = v.x + v.y + v.z + v.w;
  float sq = v.x*v.x + v.y*v.y + v.z*v.z + v.w*v.w;
#pragma unroll
  for (int m = 1; m < 64; m <<= 1) { s += __shfl_xor(s, m); sq += __shfl_xor(sq, m); }
  __shared__ float red[8];
  const int w = tid >> 6;
  if ((tid & 63) == 0) { red[w] = s; red[4 + w] = sq; }
  __syncthreads();
  s  = red[0] + red[1] + red[2] + red[3];
  sq = red[4] + red[5] + red[6] + red[7];
  const float mu   = s * (1.0f/1024.0f);
  const float var  = sq * (1.0f/1024.0f) - mu*mu;
  const float rstd = 1.0f / sqrtf(var + 1e-5f);
  const float4 gv = ((const float4*)g)[tid];
  const float4 bv = ((const float4*)bb)[tid];
  float o4[4];
  o4[0] = (v.x - mu)*rstd*gv.x + bv.x;
  o4[1] = (v.y - mu)*rstd*gv.y + bv.y;
  o4[2] = (v.z - mu)*rstd*gv.z + bv.z;
  o4[3] = (v.w - mu)*rstd*gv.w + bv.w;
  const long base = (long)t * 1024 + tid * 4;
  if (oh) {
    f16x4 hv, lv;
#pragma unroll
    for (int i = 0; i < 4; ++i) {
      hv[i] = (f16)o4[i];
      lv[i] = (f16)((o4[i] - (float)hv[i]) * LO_SCALE);
    }
    *(f16x4*)(oh + base) = hv;
    *(f16x4*)(ol + base) = lv;
  }
  if (o1) {
    f16x4 ov = {(f16)o4[0], (f16)o4[1], (f16)o4[2], (f16)o4[3]};
    *(f16x4*)(o1 + base) = ov;
  }
  if (of) *(float4*)(of + base) = make_float4(o4[0], o4[1], o4[2], o4[3]);
}

// ---------------- split-f16 GEMM: C = A @ B^T (fp32-faithful) ----------------
// 128x128 tile, BK=32, 4 waves (2x2 of 64x64), global_load_lds staging.
#define GM_QKV 0   // C -> split f16 (qkv buffer)
#define GM_WO  1   // C -> fp32 x2 = xres + rs * acc

template<int MODE>
__global__ __launch_bounds__(256, 2) void gemm_split_kernel(
    const f16* __restrict__ Ah, const f16* __restrict__ Al,
    const f16* __restrict__ Bh, const f16* __restrict__ Bl,
    f16* __restrict__ Ch, f16* __restrict__ Cl,
    float* __restrict__ Cf,
    const float* __restrict__ xres, const float* __restrict__ rsp,
    int N, int K)
{
  __shared__ __align__(16) f16 sAh[128*32], sAl[128*32], sBh[128*32], sBl[128*32];
  const int tid = threadIdx.x;
  const int l = tid & 63, w = tid >> 6;
  const int wm = w >> 1, wn = w & 1;
  const int tm0 = blockIdx.y * 128, tn0 = blockIdx.x * 128;
  const int kg = l >> 4, r16 = l & 15;
  const int srow = w * 32 + (l >> 2);
  const int scol = (l & 3) * 8;
  const int ldsbase = w * 1024;

  f32x4 am[4][4] = {};  // main: ah*bh              (scale 256)
  f32x4 ac[4][4] = {};  // corr: ah*bl + al*bh      (scale 256*2048)

  for (int k0 = 0; k0 < K; k0 += 32) {
#pragma unroll
    for (int i = 0; i < 2; ++i) {
      const int row = srow + i * 16;
      const long aoff = (long)(tm0 + row) * K + k0 + scol;
      const long boff = (long)(tn0 + row) * K + k0 + scol;
      const int lo = ldsbase + i * 512;
      gl_lds16(Ah + aoff, &sAh[lo]);
      gl_lds16(Al + aoff, &sAl[lo]);
      gl_lds16(Bh + boff, &sBh[lo]);
      gl_lds16(Bl + boff, &sBl[lo]);
    }
    __syncthreads();
    f16x8 ah[4], al[4], bh[4], bl[4];
#pragma unroll
    for (int m = 0; m < 4; ++m) {
      const int ro = (wm*64 + m*16 + r16) * 32 + kg*8;
      ah[m] = *(const f16x8*)&sAh[ro];
      al[m] = *(const f16x8*)&sAl[ro];
    }
#pragma unroll
    for (int n = 0; n < 4; ++n) {
      const int ro = (wn*64 + n*16 + r16) * 32 + kg*8;
      bh[n] = *(const f16x8*)&sBh[ro];
      bl[n] = *(const f16x8*)&sBl[ro];
    }
#pragma unroll
    for (int m = 0; m < 4; ++m)
#pragma unroll
      for (int n = 0; n < 4; ++n) {
        am[m][n] = MFMA16(ah[m], bh[n], am[m][n]);
        ac[m][n] = MFMA16(ah[m], bl[n], ac[m][n]);
        ac[m][n] = MFMA16(al[m], bh[n], ac[m][n]);
      }
    __syncthreads();
  }

  const float rs = (MODE == GM_WO) ? rsp[0] : 0.0f;
#pragma unroll
  for (int m = 0; m < 4; ++m)
#pragma unroll
    for (int n = 0; n < 4; ++n)
#pragma unroll
      for (int r = 0; r < 4; ++r) {
        const int row = tm0 + wm*64 + m*16 + kg*4 + r;
        const int col = tn0 + wn*64 + n*16 + r16;
        const long idx = (long)row * N + col;
        const float v = am[m][n][r] * INV_W + ac[m][n][r] * INV_WLO;
        if (MODE == GM_QKV) {
          const f16 vh = (f16)v;
          Ch[idx] = vh;
          Cl[idx] = (f16)((v - (float)vh) * LO_SCALE);
        } else {
          Cf[idx] = xres[idx] + rs * v;
        }
      }
}

// ---------------- flash attention (split-f16, fp32-faithful) ----------------
// grid (16 qtiles, 64 b*h). 4 waves x 16 q-rows. KV tiles of 64.
__global__ __launch_bounds__(256, 2) void attn_kernel(
    const f16* __restrict__ qkh, const f16* __restrict__ qkl,
    f16* __restrict__ ctxh, f16* __restrict__ ctxl)
{
  __shared__ __align__(16) f16 sKh[64*64], sKl[64*64], sVh[64*64], sVl[64*64];
  __shared__ __align__(16) f16 sPh[4*16*64], sPl[4*16*64];
  const int qt = blockIdx.x;
  const int bh = blockIdx.y;
  const int b = bh >> 4, h = bh & 15;
  const int tid = threadIdx.x;
  const int l = tid & 63, w = tid >> 6;
  const int kg = l >> 4, r16 = l & 15;

  // Q fragments (A operand: row = l&15, k = kg*8..)
  const long qbase = (long)(b*1024 + qt*64 + w*16 + r16) * 3072 + h * 64;
  f16x8 aqh[2], aql[2];
#pragma unroll
  for (int c = 0; c < 2; ++c) {
    aqh[c] = *(const f16x8*)(qkh + qbase + c*32 + kg*8);
    aql[c] = *(const f16x8*)(qkl + qbase + c*32 + kg*8);
  }

  f32x4 om[4] = {}; f32x4 oc[4] = {};
  float mrun[4] = {-INFINITY, -INFINITY, -INFINITY, -INFINITY};
  float lrun[4] = {0.f, 0.f, 0.f, 0.f};

  for (int kv0 = 0; kv0 < 1024; kv0 += 64) {
    // stage K (row-major, XOR-swizzled) and V (transposed, XOR-swizzled)
#pragma unroll
    for (int cc = 0; cc < 2; ++cc) {
      const int c = tid + cc * 256;          // 512 chunks of 8 elems
      const int row = c >> 3, c8 = c & 7;
      const long gb = (long)(b*1024 + kv0 + row) * 3072 + 1024 + h*64 + c8*8;
      const int slot = row*8 + (c8 ^ (row & 7));
      *(uint4*)&sKh[slot*8] = *(const uint4*)(qkh + gb);
      *(uint4*)&sKl[slot*8] = *(const uint4*)(qkl + gb);
      f16 vh8[8], vl8[8];
      *(uint4*)vh8 = *(const uint4*)(qkh + gb + 1024);
      *(uint4*)vl8 = *(const uint4*)(qkl + gb + 1024);
#pragma unroll
      for (int e2 = 0; e2 < 8; ++e2) {
        const int d = c8*8 + e2;
        const int ci = d*64 + (row ^ ((d & 7) << 3));
        sVh[ci] = vh8[e2];
        sVl[ci] = vl8[e2];
      }
    }
    __syncthreads();

    // S = Q @ K^T (split)
    f32x4 sm[4] = {}; f32x4 sc[4] = {};
#pragma unroll
    for (int n = 0; n < 4; ++n) {
      const int krow = n*16 + r16;
#pragma unroll
      for (int c = 0; c < 2; ++c) {
        const int slot = krow*8 + ((c*4 + kg) ^ (krow & 7));
        const f16x8 kh = *(const f16x8*)&sKh[slot*8];
        const f16x8 kl = *(const f16x8*)&sKl[slot*8];
        sm[n] = MFMA16(aqh[c], kh, sm[n]);
        sc[n] = MFMA16(aqh[c], kl, sc[n]);
        sc[n] = MFMA16(aql[c], kh, sc[n]);
      }
    }
    float sval[4][4];
#pragma unroll
    for (int n = 0; n < 4; ++n)
#pragma unroll
      for (int r = 0; r < 4; ++r)
        sval[n][r] = (sm[n][r] + sc[n][r] * INV_LO) * 0.125f;

    // online softmax; row r of C-frag lives in this 16-lane group at reg r
    float pv[4][4];
#pragma unroll
    for (int r = 0; r < 4; ++r) {
      float mx = fmaxf(fmaxf(sval[0][r], sval[1][r]), fmaxf(sval[2][r], sval[3][r]));
#pragma unroll
      for (int msk = 1; msk < 16; msk <<= 1) mx = fmaxf(mx, __shfl_xor(mx, msk));
      const float mnew = fmaxf(mrun[r], mx);
      const float fsc = expf(mrun[r] - mnew);
      mrun[r] = mnew;
      lrun[r] *= fsc;
#pragma unroll
      for (int n = 0; n < 4; ++n) { om[n][r] *= fsc; oc[n][r] *= fsc; }
      float ps = 0.f;
#pragma unroll
      for (int n = 0; n < 4; ++n) {
        const float p = expf(sval[n][r] - mnew);
        pv[n][r] = p;
        ps += p;
      }
#pragma unroll
      for (int msk = 1; msk < 16; msk <<= 1) ps += __shfl_xor(ps, msk);
      lrun[r] += ps;
    }

    // P -> LDS (per-wave region, split, swizzled for A-operand re-read)
#pragma unroll
    for (int n = 0; n < 4; ++n)
#pragma unroll
      for (int r = 0; r < 4; ++r) {
        const int qr = kg*4 + r;
        const int kvc = n*16 + r16;
        const int idx = w*1024 + qr*64 + (kvc ^ ((qr & 7) << 3));
        const float p = pv[n][r];
        const f16 ph = (f16)p;
        sPh[idx] = ph;
        sPl[idx] = (f16)((p - (float)ph) * LO_SCALE);
      }

    // O += P @ V (split)
#pragma unroll
    for (int c = 0; c < 2; ++c) {
      const int pidx = w*1024 + r16*64 + ((c*32 + kg*8) ^ ((r16 & 7) << 3));
      const f16x8 ph = *(const f16x8*)&sPh[pidx];
      const f16x8 pl = *(const f16x8*)&sPl[pidx];
#pragma unroll
      for (int n = 0; n < 4; ++n) {
        const int d = n*16 + r16;
        const int vi = d*64 + ((c*32 + kg*8) ^ ((d & 7) << 3));
        const f16x8 vh = *(const f16x8*)&sVh[vi];
        const f16x8 vl = *(const f16x8*)&sVl[vi];
        om[n] = MFMA16(ph, vh, om[n]);
        oc[n] = MFMA16(ph, vl, oc[n]);
        oc[n] = MFMA16(pl, vh, oc[n]);
      }
    }
    __syncthreads();
  }

  float inv[4];
#pragma unroll
  for (int r = 0; r < 4; ++r) inv[r] = 1.0f / lrun[r];
#pragma unroll
  for (int n = 0; n < 4; ++n)
#pragma unroll
    for (int r = 0; r < 4; ++r) {
      const long t = (long)(b*1024 + qt*64 + w*16 + kg*4 + r);
      const int col = h*64 + n*16 + r16;
      const float val = (om[n][r] + oc[n][r] * INV_LO) * inv[r];
      const f16 vh = (f16)val;
      ctxh[t*1024 + col] = vh;
      ctxl[t*1024 + col] = (f16)((val - (float)vh) * LO_SCALE);
    }
}

// ---------------- router (fp32 exact) ----------------
__global__ __launch_bounds__(256) void router_kernel(
    const float* __restrict__ nx2f, const float* __restrict__ Wg,
    float* __restrict__ outLogits, float* __restrict__ outEnt,
    int* __restrict__ cnt, int* __restrict__ tok,
    int* __restrict__ pidx, float* __restrict__ pw)
{
  const int tid = threadIdx.x;
  const int l = tid & 63, w = tid >> 6;
  const int t = blockIdx.x * 4 + w;
  const float4* xr = (const float4*)(nx2f + (long)t * 1024);
  float4 xv[4];
#pragma unroll
  for (int i = 0; i < 4; ++i) xv[i] = xr[l*4 + i];
  float lg[8];
#pragma unroll
  for (int e = 0; e < 8; ++e) {
    const float4* wr = (const float4*)(Wg + e * 1024);
    float s = 0.f;
#pragma unroll
    for (int i = 0; i < 4; ++i) {
      const float4 wv = wr[l*4 + i];
      s += xv[i].x*wv.x + xv[i].y*wv.y + xv[i].z*wv.z + xv[i].w*wv.w;
    }
#pragma unroll
    for (int msk = 1; msk < 64; msk <<= 1) s += __shfl_xor(s, msk);
    lg[e] = s;
  }
  float mx = lg[0];
#pragma unroll
  for (int e = 1; e < 8; ++e) mx = fmaxf(mx, lg[e]);
  float den = 0.f, pe[8];
#pragma unroll
  for (int e = 0; e < 8; ++e) { pe[e] = expf(lg[e] - mx); den += pe[e]; }
  const float invd = 1.0f / den;
  float ent = 0.f;
#pragma unroll
  for (int e = 0; e < 8; ++e) {
    const float p = pe[e] * invd;
    ent -= p * logf(fmaxf(p, 1e-6f));
  }
  // top-2 on logits (monotone with probs; lowest index wins ties like lax.top_k)
  int s0 = 0; float v0 = lg[0];
#pragma unroll
  for (int e = 1; e < 8; ++e) if (lg[e] > v0) { v0 = lg[e]; s0 = e; }
  int s1 = (s0 == 0) ? 1 : 0; float v1 = -INFINITY;
#pragma unroll
  for (int e = 0; e < 8; ++e) if (e != s0 && lg[e] > v1) { v1 = lg[e]; s1 = e; }
  float w0 = expf(v0 - mx) * invd;
  float w1 = expf(v1 - mx) * invd;
  const float wn = 1.0f / (w0 + w1);
  w0 *= wn; w1 *= wn;

  float myv = lg[0];
#pragma unroll
  for (int e = 1; e < 8; ++e) myv = (l == e) ? lg[e] : myv;
  if (l < 8) outLogits[t*8 + l] = myv;

  if (l == 0) {
    atomicAdd(outEnt, ent * (1.0f / 4096.0f));
    const int sl0 = atomicAdd(&cnt[s0], 1);
    tok[s0*4096 + sl0] = t;
    pidx[t*2 + 0] = s0*4096 + sl0;
    pw[t*2 + 0] = w0;
    const int sl1 = atomicAdd(&cnt[s1], 1);
    tok[s1*4096 + sl1] = t;
    pidx[t*2 + 1] = s1*4096 + sl1;
    pw[t*2 + 1] = w1;
  }
}

__global__ void init_kernel(int* cnt, float* ent) {
  const int i = threadIdx.x;
  if (i < 8) cnt[i] = 0;
  if (i == 8) *ent = 0.f;
}

__global__ void finalize_kernel(const int* __restrict__ cnt, int* __restrict__ offs) {
  if (threadIdx.x == 0) {
    int o = 0;
#pragma unroll
    for (int e = 0; e < 8; ++e) { offs[e] = o; o += cnt[e]; }
  }
}

// ---------------- MoE expert GEMMs (plain f16, routed tokens only) ----------
#define GM_FFN1 0  // A = gather(nx2 via tok), epilogue gelu
#define GM_FFN2 1  // A = h rows at offs[e], plain out

template<int MODE>
__global__ __launch_bounds__(256, 2) void gemm_moe_kernel(
    const f16* __restrict__ A, const f16* __restrict__ Bw,
    f16* __restrict__ C, int N, int K,
    const int* __restrict__ tok, const int* __restrict__ cnt, const int* __restrict__ offs)
{
  __shared__ __align__(16) f16 sA[128*32], sB[128*32];
  const int e = blockIdx.z;
  const int cntE = cnt[e];
  const int tm0 = blockIdx.y * 128;
  if (tm0 >= cntE) return;
  const int rowOff = offs[e];
  const f16* Bp = Bw + (long)e * N * K;
  const int tid = threadIdx.x;
  const int l = tid & 63, w = tid >> 6;
  const int wm = w >> 1, wn = w & 1;
  const int tn0 = blockIdx.x * 128;
  const int kg = l >> 4, r16 = l & 15;
  const int srow = w*32 + (l >> 2);
  const int scol = (l & 3) * 8;
  const int ldsbase = w * 1024;

  // per-thread staging source rows (constant across K)
  long arow[2];
#pragma unroll
  for (int i = 0; i < 2; ++i) {
    int r = tm0 + srow + i*16;
    if (r > cntE - 1) r = cntE - 1;
    arow[i] = (MODE == GM_FFN1) ? (long)tok[e*4096 + r] : (long)(rowOff + r);
  }

  f32x4 acc[4][4] = {};
  for (int k0 = 0; k0 < K; k0 += 32) {
#pragma unroll
    for (int i = 0; i < 2; ++i) {
      const int row = srow + i*16;
      const int lo = ldsbase + i*512;
      gl_lds16(A + arow[i]*K + k0 + scol, &sA[lo]);
      gl_lds16(Bp + (long)(tn0 + row)*K + k0 + scol, &sB[lo]);
    }
    __syncthreads();
    f16x8 af[4], bfr[4];
#pragma unroll
    for (int m = 0; m < 4; ++m)
      af[m] = *(const f16x8*)&sA[(wm*64 + m*16 + r16)*32 + kg*8];
#pragma unroll
    for (int n = 0; n < 4; ++n)
      bfr[n] = *(const f16x8*)&sB[(wn*64 + n*16 + r16)*32 + kg*8];
#pragma unroll
    for (int m = 0; m < 4; ++m)
#pragma unroll
      for (int n = 0; n < 4; ++n)
        acc[m][n] = MFMA16(af[m], bfr[n], acc[m][n]);
    __syncthreads();
  }

#pragma unroll
  for (int m = 0; m < 4; ++m)
#pragma unroll
    for (int n = 0; n < 4; ++n)
#pragma unroll
      for (int r = 0; r < 4; ++r) {
        const int rr = tm0 + wm*64 + m*16 + kg*4 + r;
        if (rr < cntE) {
          const int col = tn0 + wn*64 + n*16 + r16;
          float v = acc[m][n][r];
          if (MODE == GM_FFN1) v = 0.5f * v * (1.0f + erff(v * 0.70710678118654752f));
          C[(long)(rowOff + rr) * N + col] = (f16)v;
        }
      }
}

// ---------------- final combine: out = x2 + rs*(w0*eo0 + w1*eo1) ------------
__global__ __launch_bounds__(256) void combine_kernel(
    const float* __restrict__ x2, const f16* __restrict__ eo,
    const int* __restrict__ pidx, const float* __restrict__ pw,
    const int* __restrict__ offs, const float* __restrict__ rsp,
    float* __restrict__ out)
{
  const int t = blockIdx.x;
  const int tid = threadIdx.x;
  const int i0 = pidx[t*2], i1 = pidx[t*2 + 1];
  const float w0 = pw[t*2], w1 = pw[t*2 + 1];
  const long r0 = (long)offs[i0 >> 12] + (i0 & 4095);
  const long r1 = (long)offs[i1 >> 12] + (i1 & 4095);
  const float rs = rsp[0];
  const float4 xv = ((const float4*)(x2 + (long)t*1024))[tid];
  const f16x4 e0 = *(const f16x4*)(eo + r0*1024 + tid*4);
  const f16x4 e1 = *(const f16x4*)(eo + r1*1024 + tid*4);
  float4 o;
  o.x = xv.x + rs * (w0*(float)e0[0] + w1*(float)e1[0]);
  o.y = xv.y + rs * (w0*(float)e0[1] + w1*(float)e1[1]);
  o.z = xv.z + rs * (w0*(float)e0[2] + w1*(float)e1[2]);
  o.w = xv.w + rs * (w0*(float)e0[3] + w1*(float)e1[3]);
  ((float4*)(out + (long)t*1024))[tid] = o;
}

// ---------------------------------------------------------------------------
extern "C" void kernel_launch(void* const* d_in, const int* in_sizes, int n_in,
                              void* d_out, int out_size, void* d_ws, size_t ws_size,
                              hipStream_t stream)
{
  const float* x    = (const float*)d_in[0];
  const float* Wqkv = (const float*)d_in[1];
  const float* Wo   = (const float*)d_in[2];
  const float* ln1g = (const float*)d_in[3];
  const float* ln1b = (const float*)d_in[4];
  const float* ln2g = (const float*)d_in[5];
  const float* ln2b = (const float*)d_in[6];
  const float* Wg   = (const float*)d_in[7];
  const float* W1   = (const float*)d_in[8];
  const float* W2   = (const float*)d_in[9];
  const float* rsp  = (const float*)d_in[10];
  float* out = (float*)d_out;

  char* p = (char*)d_ws;
  auto alloc = [&](size_t n) { char* r = p; p += (n + 255) & ~(size_t)255; return r; };
  f16*   wqh  = (f16*)alloc(3072L*1024*2);
  f16*   wql  = (f16*)alloc(3072L*1024*2);
  f16*   woh  = (f16*)alloc(1024L*1024*2);
  f16*   wol  = (f16*)alloc(1024L*1024*2);
  f16*   w1h  = (f16*)alloc(8L*2048*1024*2);
  f16*   w2h  = (f16*)alloc(8L*1024*2048*2);
  f16*   nxh  = (f16*)alloc(4096L*1024*2);
  f16*   nxl  = (f16*)alloc(4096L*1024*2);
  f16*   qkh  = (f16*)alloc(4096L*3072*2);
  f16*   qkl  = (f16*)alloc(4096L*3072*2);
  f16*   ctxh = (f16*)alloc(4096L*1024*2);
  f16*   ctxl = (f16*)alloc(4096L*1024*2);
  float* x2   = (float*)alloc(4096L*1024*4);
  f16*   nx2h = (f16*)alloc(4096L*1024*2);
  float* nx2f = (float*)alloc(4096L*1024*4);
  int*   cnt  = (int*)alloc(256);
  int*   offs = (int*)alloc(256);
  int*   tok  = (int*)alloc(8L*4096*4);
  int*   pidx = (int*)alloc(4096L*2*4);
  float* pw   = (float*)alloc(4096L*2*4);
  if ((size_t)(p - (char*)d_ws) > ws_size) return;  // ~200 MB needed
  // aliases (lifetimes disjoint):
  f16* hbuf = qkh;   // h: 8192x2048 f16 (33.5MB) over qkh+qkl (50.3MB), dead after attn
  f16* eob  = nxh;   // eo: 8192x1024 f16 (16.8MB) over nxh+nxl, dead after QKV gemm

  // 1) weight conversion
  cvt_w_kernel<<<3072*1024/4/256, 256, 0, stream>>>(Wqkv, wqh, wql, 3072*1024/4);
  cvt_w_kernel<<<1024*1024/4/256, 256, 0, stream>>>(Wo, woh, wol, 1024*1024/4);
  cvt_h_kernel<<<8*2048*1024/4/256, 256, 0, stream>>>(W1, w1h, 8*2048*1024/4);
  cvt_h_kernel<<<8*1024*2048/4/256, 256, 0, stream>>>(W2, w2h, 8*1024*2048/4);
  // 2) LN1 -> split nx
  ln_kernel<<<4096, 256, 0, stream>>>(x, ln1g, ln1b, nxh, nxl, nullptr, nullptr);
  // 3) QKV projection (split, fp32-faithful)
  gemm_split_kernel<GM_QKV><<<dim3(24, 32), 256, 0, stream>>>(
      nxh, nxl, wqh, wql, qkh, qkl, nullptr, nullptr, nullptr, 3072, 1024);
  // 4) flash attention
  attn_kernel<<<dim3(16, 64), 256, 0, stream>>>(qkh, qkl, ctxh, ctxl);
  // 5) Wo projection + residual -> x2
  gemm_split_kernel<GM_WO><<<dim3(8, 32), 256, 0, stream>>>(
      ctxh, ctxl, woh, wol, nullptr, nullptr, x2, x, rsp, 1024, 1024);
  // 6) LN2 -> f16 (MoE) + fp32 (router)
  ln_kernel<<<4096, 256, 0, stream>>>(x2, ln2g, ln2b, nullptr, nullptr, nx2h, nx2f);
  // 7) routing
  init_kernel<<<1, 64, 0, stream>>>(cnt, out + 4227072);
  router_kernel<<<1024, 256, 0, stream>>>(nx2f, Wg, out + 4194304, out + 4227072,
                                          cnt, tok, pidx, pw);
  finalize_kernel<<<1, 64, 0, stream>>>(cnt, offs);
  // 8) expert FFN (routed tokens only)
  gemm_moe_kernel<GM_FFN1><<<dim3(16, 32, 8), 256, 0, stream>>>(
      nx2h, w1h, hbuf, 2048, 1024, tok, cnt, offs);
  gemm_moe_kernel<GM_FFN2><<<dim3(8, 32, 8), 256, 0, stream>>>(
      hbuf, w2h, eob, 1024, 2048, tok, cnt, offs);
  // 9) combine + residual -> out
  combine_kernel<<<4096, 256, 0, stream>>>(x2, eob, pidx, pw, offs, rsp, out);
}

// Round 3
// 734.652 us; speedup vs baseline: 1.0722x; 1.0722x over previous
//
#include <hip/hip_runtime.h>
#include <math.h>

// ---------------------------------------------------------------------------
// EncoderLayer: LN1 -> MHA -> +res -> LN2 -> top2-MoE -> +res
// B=4 S=1024 D=1024 H=16 DK=64 E=8 DFF=2048
//
// Precision strategy:
//  - Pre-router path (LN1, QKV, attention, Wo, LN2, router) must be
//    fp32-faithful (top_k selection is discontinuous). Implemented with
//    split-f16 MFMA: a = ah + al*2^-11 (al stored prescaled x2048; weights
//    prescaled x256) -> 3 MFMAs, dual accumulators, exact pow2 merge.
//  - MoE FFN (post-selection) is plain f16 MFMA, only routed tokens computed.
// ---------------------------------------------------------------------------

typedef _Float16 f16;
typedef _Float16 f16x8 __attribute__((ext_vector_type(8)));
typedef _Float16 f16x4 __attribute__((ext_vector_type(4)));
typedef float f32x4 __attribute__((ext_vector_type(4)));

#define LO_SCALE 2048.0f
#define INV_LO   (1.0f/2048.0f)
#define INV_W    (1.0f/256.0f)
#define INV_WLO  (1.0f/(256.0f*2048.0f))

#define MFMA16(a, b, c) __builtin_amdgcn_mfma_f32_16x16x32_f16(a, b, c, 0, 0, 0)

__device__ __forceinline__ void gl_lds16(const void* g, void* l) {
  __builtin_amdgcn_global_load_lds(
      (const __attribute__((address_space(1))) void*)g,
      (__attribute__((address_space(3))) void*)l, 16, 0, 0);
}

__device__ __forceinline__ unsigned int pk2(f16 a, f16 b) {
  union { f16 h[2]; unsigned int u; } x; x.h[0] = a; x.h[1] = b; return x.u;
}

// ---------------- weight conversion ----------------
__global__ __launch_bounds__(256) void cvt_w_kernel(
    const float* __restrict__ in, f16* __restrict__ oh, f16* __restrict__ ol, int n4) {
  const int i = blockIdx.x * 256 + threadIdx.x;
  if (i >= n4) return;
  const float4 v = ((const float4*)in)[i];
  f16x4 hv, lv;
  float a;
  a = v.x * 256.0f; hv[0] = (f16)a; lv[0] = (f16)((a - (float)hv[0]) * LO_SCALE);
  a = v.y * 256.0f; hv[1] = (f16)a; lv[1] = (f16)((a - (float)hv[1]) * LO_SCALE);
  a = v.z * 256.0f; hv[2] = (f16)a; lv[2] = (f16)((a - (float)hv[2]) * LO_SCALE);
  a = v.w * 256.0f; hv[3] = (f16)a; lv[3] = (f16)((a - (float)hv[3]) * LO_SCALE);
  ((f16x4*)oh)[i] = hv;
  ((f16x4*)ol)[i] = lv;
}

__global__ __launch_bounds__(256) void cvt_h_kernel(
    const float* __restrict__ in, f16* __restrict__ out, int n4) {
  const int i = blockIdx.x * 256 + threadIdx.x;
  if (i >= n4) return;
  const float4 v = ((const float4*)in)[i];
  f16x4 ov = {(f16)v.x, (f16)v.y, (f16)v.z, (f16)v.w};
  ((f16x4*)out)[i] = ov;
}

// ---------------- layernorm ----------------
__global__ __launch_bounds__(256) void ln_kernel(
    const float* __restrict__ x, const float* __restrict__ g, const float* __restrict__ bb,
    f16* __restrict__ oh, f16* __restrict__ ol,
    f16* __restrict__ o1, float* __restrict__ of)
{
  const int t = blockIdx.x, tid = threadIdx.x;
  const float4 v = ((const float4*)(x + (long)t * 1024))[tid];
  float s  = v.x + v.y + v.z + v.w;
  float sq = v.x*v.x + v.y*v.y + v.z*v.z + v.w*v.w;
#pragma unroll
  for (int m = 1; m < 64; m <<= 1) { s += __shfl_xor(s, m); sq += __shfl_xor(sq, m); }
  __shared__ float red[8];
  const int w = tid >> 6;
  if ((tid & 63) == 0) { red[w] = s; red[4 + w] = sq; }
  __syncthreads();
  s  = red[0] + red[1] + red[2] + red[3];
  sq = red[4] + red[5] + red[6] + red[7];
  const float mu   = s * (1.0f/1024.0f);
  const float var  = sq * (1.0f/1024.0f) - mu*mu;
  const float rstd = 1.0f / sqrtf(var + 1e-5f);
  const float4 gv = ((const float4*)g)[tid];
  const float4 bv = ((const float4*)bb)[tid];
  float o4[4];
  o4[0] = (v.x - mu)*rstd*gv.x + bv.x;
  o4[1] = (v.y - mu)*rstd*gv.y + bv.y;
  o4[2] = (v.z - mu)*rstd*gv.z + bv.z;
  o4[3] = (v.w - mu)*rstd*gv.w + bv.w;
  const long base = (long)t * 1024 + tid * 4;
  if (oh) {
    f16x4 hv, lv;
#pragma unroll
    for (int i = 0; i < 4; ++i) {
      hv[i] = (f16)o4[i];
      lv[i] = (f16)((o4[i] - (float)hv[i]) * LO_SCALE);
    }
    *(f16x4*)(oh + base) = hv;
    *(f16x4*)(ol + base) = lv;
  }
  if (o1) {
    f16x4 ov = {(f16)o4[0], (f16)o4[1], (f16)o4[2], (f16)o4[3]};
    *(f16x4*)(o1 + base) = ov;
  }
  if (of) *(float4*)(of + base) = make_float4(o4[0], o4[1], o4[2], o4[3]);
}

// ---------------- split-f16 GEMM: C = A @ B^T ----------------
#define GM_QKV 0
#define GM_WO  1

template<int MODE>
__global__ __launch_bounds__(256, 2) void gemm_split_kernel(
    const f16* __restrict__ Ah, const f16* __restrict__ Al,
    const f16* __restrict__ Bh, const f16* __restrict__ Bl,
    f16* __restrict__ Ch, f16* __restrict__ Cl,
    float* __restrict__ Cf,
    const float* __restrict__ xres, const float* __restrict__ rsp,
    int N, int K)
{
  __shared__ __align__(16) f16 sAh[128*32], sAl[128*32], sBh[128*32], sBl[128*32];
  const int tid = threadIdx.x;
  const int l = tid & 63, w = tid >> 6;
  const int wm = w >> 1, wn = w & 1;
  const int tm0 = blockIdx.y * 128, tn0 = blockIdx.x * 128;
  const int kg = l >> 4, r16 = l & 15;
  const int srow = w * 32 + (l >> 2);
  const int scol = (l & 3) * 8;
  const int ldsbase = w * 1024;

  f32x4 am[4][4] = {};
  f32x4 ac[4][4] = {};

  for (int k0 = 0; k0 < K; k0 += 32) {
#pragma unroll
    for (int i = 0; i < 2; ++i) {
      const int row = srow + i * 16;
      const long aoff = (long)(tm0 + row) * K + k0 + scol;
      const long boff = (long)(tn0 + row) * K + k0 + scol;
      const int lo = ldsbase + i * 512;
      gl_lds16(Ah + aoff, &sAh[lo]);
      gl_lds16(Al + aoff, &sAl[lo]);
      gl_lds16(Bh + boff, &sBh[lo]);
      gl_lds16(Bl + boff, &sBl[lo]);
    }
    __syncthreads();
    f16x8 ah[4], al[4], bh[4], bl[4];
#pragma unroll
    for (int m = 0; m < 4; ++m) {
      const int ro = (wm*64 + m*16 + r16) * 32 + kg*8;
      ah[m] = *(const f16x8*)&sAh[ro];
      al[m] = *(const f16x8*)&sAl[ro];
    }
#pragma unroll
    for (int n = 0; n < 4; ++n) {
      const int ro = (wn*64 + n*16 + r16) * 32 + kg*8;
      bh[n] = *(const f16x8*)&sBh[ro];
      bl[n] = *(const f16x8*)&sBl[ro];
    }
#pragma unroll
    for (int m = 0; m < 4; ++m)
#pragma unroll
      for (int n = 0; n < 4; ++n) {
        am[m][n] = MFMA16(ah[m], bh[n], am[m][n]);
        ac[m][n] = MFMA16(ah[m], bl[n], ac[m][n]);
        ac[m][n] = MFMA16(al[m], bh[n], ac[m][n]);
      }
    __syncthreads();
  }

  const float rs = (MODE == GM_WO) ? rsp[0] : 0.0f;
#pragma unroll
  for (int m = 0; m < 4; ++m)
#pragma unroll
    for (int n = 0; n < 4; ++n)
#pragma unroll
      for (int r = 0; r < 4; ++r) {
        const int row = tm0 + wm*64 + m*16 + kg*4 + r;
        const int col = tn0 + wn*64 + n*16 + r16;
        const long idx = (long)row * N + col;
        const float v = am[m][n][r] * INV_W + ac[m][n][r] * INV_WLO;
        if (MODE == GM_QKV) {
          const f16 vh = (f16)v;
          Ch[idx] = vh;
          Cl[idx] = (f16)((v - (float)vh) * LO_SCALE);
        } else {
          Cf[idx] = xres[idx] + rs * v;
        }
      }
}

// ---------------- V transpose: qkv V-slice -> vT[bh][d][t] (split) ----------
__global__ __launch_bounds__(256) void vt_kernel(
    const f16* __restrict__ qkh, const f16* __restrict__ qkl,
    f16* __restrict__ vTh, f16* __restrict__ vTl)
{
  __shared__ __align__(16) f16 sH[64*72], sL[64*72];
  const int bh = blockIdx.x, tt = blockIdx.y;
  const int b = bh >> 4, h = bh & 15;
  const int t0 = tt * 64;
  const int tid = threadIdx.x;
#pragma unroll
  for (int cc = 0; cc < 2; ++cc) {
    const int c = tid + cc*256;
    const int row = c >> 3, p = c & 7;
    const int pos = p ^ (row & 7) ^ (row >> 3);
    const long src = (long)(b*1024 + t0 + row)*3072 + 2048 + h*64 + p*8;
    *(uint4*)&sH[row*72 + pos*8] = *(const uint4*)(qkh + src);
    *(uint4*)&sL[row*72 + pos*8] = *(const uint4*)(qkl + src);
  }
  __syncthreads();
#pragma unroll
  for (int cc = 0; cc < 2; ++cc) {
    const int c = tid + cc*256;
    const int d = c >> 3, k8 = c & 7;
    union { f16 h[8]; uint4 u; } oh, ol;
#pragma unroll
    for (int e = 0; e < 8; ++e) {
      const int k = k8*8 + e;
      const int pos = (d >> 3) ^ (k & 7) ^ (k >> 3);
      oh.h[e] = sH[k*72 + pos*8 + (d & 7)];
      ol.h[e] = sL[k*72 + pos*8 + (d & 7)];
    }
    const long dst = ((long)bh*64 + d)*1024 + t0 + k8*8;
    *(uint4*)(vTh + dst) = oh.u;
    *(uint4*)(vTl + dst) = ol.u;
  }
}

// ---------------- flash attention (split-f16, swapped-operand S^T) ---------
// grid (64 bh, 16 qt). 4 waves; wave w owns q-rows w*16 + r16 (lane-local q).
__global__ __launch_bounds__(256, 2) void attn_kernel(
    const f16* __restrict__ qkh, const f16* __restrict__ qkl,
    const f16* __restrict__ vTh, const f16* __restrict__ vTl,
    f16* __restrict__ ctxh, f16* __restrict__ ctxl)
{
  __shared__ __align__(16) f16 smem[16384];       // sKh|sKl|sVh|sVl, 8KB each
  f16* sKh = smem;
  f16* sKl = smem + 4096;
  f16* sVh = smem + 8192;
  f16* sVl = smem + 12288;

  const int bh = blockIdx.x, qt = blockIdx.y;
  const int b = bh >> 4, h = bh & 15;
  const int tid = threadIdx.x;
  const int l = tid & 63, w = tid >> 6;
  const int kg = l >> 4, r16 = l & 15;
  const int ls0 = ((l & 16) << 1) + r16;          // partner lanes for P exchange
  const int ls1 = ls0 + 16;
  const bool hi = (l & 32) != 0;

  // ---- stage Q tile (coalesced) and read B-frags ----
  {
#pragma unroll
    for (int cc = 0; cc < 2; ++cc) {
      const int c = tid + cc*256;
      const int row = c >> 3, p = c & 7;
      const int sp = p ^ (row & 7);
      const long src = (long)(b*1024 + qt*64 + row)*3072 + h*64 + sp*8;
      gl_lds16(qkh + src, &sKh[c*8]);
      gl_lds16(qkl + src, &sKl[c*8]);
    }
    __syncthreads();
  }
  f16x8 bqh[2], bql[2];
  {
    const int qrow = w*16 + r16;
#pragma unroll
    for (int c = 0; c < 2; ++c) {
      const int off = qrow*64 + (((c*4 + kg) ^ (qrow & 7))) * 8;
      bqh[c] = *(const f16x8*)&sKh[off];
      bql[c] = *(const f16x8*)&sKl[off];
    }
    __syncthreads();
  }

  f32x4 om[4] = {}, oc[4] = {};                   // O^T[d = n*16+kg*4+r][q=r16]
  float mrun = -INFINITY, lrun = 0.f;

  for (int kv0 = 0; kv0 < 1024; kv0 += 64) {
    // ---- stage K rows and V^T rows (pre-swizzled source, linear LDS) ----
#pragma unroll
    for (int cc = 0; cc < 2; ++cc) {
      const int c = tid + cc*256;
      const int row = c >> 3, p = c & 7;
      const int sp = p ^ (row & 7);
      const long ksrc = (long)(b*1024 + kv0 + row)*3072 + 1024 + h*64 + sp*8;
      gl_lds16(qkh + ksrc, &sKh[c*8]);
      gl_lds16(qkl + ksrc, &sKl[c*8]);
      const long vsrc = ((long)bh*64 + row)*1024 + kv0 + sp*8;
      gl_lds16(vTh + vsrc, &sVh[c*8]);
      gl_lds16(vTl + vsrc, &sVl[c*8]);
    }
    __syncthreads();

    // ---- S^T = K @ Q^T (split) ----
    f32x4 sm[4] = {}, sc[4] = {};
#pragma unroll
    for (int n = 0; n < 4; ++n) {
      const int krow = n*16 + r16;
#pragma unroll
      for (int c = 0; c < 2; ++c) {
        const int ko = krow*64 + (((c*4 + kg) ^ (krow & 7))) * 8;
        const f16x8 kh = *(const f16x8*)&sKh[ko];
        const f16x8 kl = *(const f16x8*)&sKl[ko];
        sm[n] = MFMA16(kh, bqh[c], sm[n]);
        sc[n] = MFMA16(kh, bql[c], sc[n]);
        sc[n] = MFMA16(kl, bqh[c], sc[n]);
      }
    }

    // ---- lane-local online softmax (q = r16; kv spread over kg x reg) ----
    float sv[4][4];
    float mx = -INFINITY;
#pragma unroll
    for (int n = 0; n < 4; ++n)
#pragma unroll
      for (int r = 0; r < 4; ++r) {
        sv[n][r] = (sm[n][r] + sc[n][r] * INV_LO) * 0.125f;
        mx = fmaxf(mx, sv[n][r]);
      }
    mx = fmaxf(mx, __shfl_xor(mx, 16));
    mx = fmaxf(mx, __shfl_xor(mx, 32));
    const float mnew = fmaxf(mrun, mx);
    const float fsc = __expf(mrun - mnew);
    mrun = mnew;
    lrun *= fsc;
#pragma unroll
    for (int n = 0; n < 4; ++n) { om[n] *= fsc; oc[n] *= fsc; }
    float pp[4][4];
    float ps = 0.f;
#pragma unroll
    for (int n = 0; n < 4; ++n)
#pragma unroll
      for (int r = 0; r < 4; ++r) {
        pp[n][r] = __expf(sv[n][r] - mnew);
        ps += pp[n][r];
      }
    ps += __shfl_xor(ps, 16);
    ps += __shfl_xor(ps, 32);
    lrun += ps;

    // ---- split P into packed f16x2 words ----
    unsigned int wh_[4][2], wl_[4][2];
#pragma unroll
    for (int n = 0; n < 4; ++n)
#pragma unroll
      for (int hh = 0; hh < 2; ++hh) {
        const float p0 = pp[n][2*hh], p1 = pp[n][2*hh+1];
        const f16 h0 = (f16)p0, h1 = (f16)p1;
        wh_[n][hh] = pk2(h0, h1);
        wl_[n][hh] = pk2((f16)((p0 - (float)h0) * LO_SCALE),
                         (f16)((p1 - (float)h1) * LO_SCALE));
      }

    // ---- O^T += V^T @ P^T (P frags via cross-lane exchange) ----
#pragma unroll
    for (int c = 0; c < 2; ++c) {
      union { unsigned int u[4]; f16x8 v; } pah, pal;
      {
        const unsigned int* A = wh_[2*c];
        const unsigned int* B = wh_[2*c+1];
        unsigned int t0 = __shfl((int)A[0], ls0), u0 = __shfl((int)B[0], ls0);
        unsigned int t1 = __shfl((int)A[1], ls0), u1 = __shfl((int)B[1], ls0);
        unsigned int t2 = __shfl((int)A[0], ls1), u2 = __shfl((int)B[0], ls1);
        unsigned int t3 = __shfl((int)A[1], ls1), u3 = __shfl((int)B[1], ls1);
        pah.u[0] = hi ? u0 : t0; pah.u[1] = hi ? u1 : t1;
        pah.u[2] = hi ? u2 : t2; pah.u[3] = hi ? u3 : t3;
      }
      {
        const unsigned int* A = wl_[2*c];
        const unsigned int* B = wl_[2*c+1];
        unsigned int t0 = __shfl((int)A[0], ls0), u0 = __shfl((int)B[0], ls0);
        unsigned int t1 = __shfl((int)A[1], ls0), u1 = __shfl((int)B[1], ls0);
        unsigned int t2 = __shfl((int)A[0], ls1), u2 = __shfl((int)B[0], ls1);
        unsigned int t3 = __shfl((int)A[1], ls1), u3 = __shfl((int)B[1], ls1);
        pal.u[0] = hi ? u0 : t0; pal.u[1] = hi ? u1 : t1;
        pal.u[2] = hi ? u2 : t2; pal.u[3] = hi ? u3 : t3;
      }
#pragma unroll
      for (int n = 0; n < 4; ++n) {
        const int vrow = n*16 + r16;
        const int vo = vrow*64 + (((c*4 + kg) ^ (vrow & 7))) * 8;
        const f16x8 vh = *(const f16x8*)&sVh[vo];
        const f16x8 vl = *(const f16x8*)&sVl[vo];
        om[n] = MFMA16(vh, pah.v, om[n]);
        oc[n] = MFMA16(vh, pal.v, oc[n]);
        oc[n] = MFMA16(vl, pah.v, oc[n]);
      }
    }
    __syncthreads();
  }

  // ---- epilogue: normalize, transpose O^T -> ctx rows via LDS ----
  const float inv = 1.0f / lrun;
  f16 oh16[4][4], ol16[4][4];
#pragma unroll
  for (int n = 0; n < 4; ++n)
#pragma unroll
    for (int r = 0; r < 4; ++r) {
      const float v = (om[n][r] + oc[n][r] * INV_LO) * inv;
      oh16[n][r] = (f16)v;
      ol16[n][r] = (f16)((v - (float)oh16[n][r]) * LO_SCALE);
    }
  f16* sT = smem;                                 // 64 q x 72 d
  const int qloc = w*16 + r16;
#pragma unroll
  for (int pass = 0; pass < 2; ++pass) {
#pragma unroll
    for (int n = 0; n < 4; ++n) {
      f16x4 v4;
#pragma unroll
      for (int r = 0; r < 4; ++r) v4[r] = pass ? ol16[n][r] : oh16[n][r];
      *(f16x4*)&sT[qloc*72 + n*16 + kg*4] = v4;
    }
    __syncthreads();
    f16* dst = pass ? ctxl : ctxh;
#pragma unroll
    for (int cc = 0; cc < 2; ++cc) {
      const int c = tid + cc*256;
      const int q = c >> 3, dc = c & 7;
      const uint4 vv = *(const uint4*)&sT[q*72 + dc*8];
      *(uint4*)(dst + (long)(b*1024 + qt*64 + q)*1024 + h*64 + dc*8) = vv;
    }
    __syncthreads();
  }
}

// ---------------- router (fp32 exact) ----------------
__global__ __launch_bounds__(256) void router_kernel(
    const float* __restrict__ nx2f, const float* __restrict__ Wg,
    float* __restrict__ outLogits, float* __restrict__ outEnt,
    int* __restrict__ cnt, int* __restrict__ tok,
    int* __restrict__ pidx, float* __restrict__ pw)
{
  const int tid = threadIdx.x;
  const int l = tid & 63, w = tid >> 6;
  const int t = blockIdx.x * 4 + w;
  const float4* xr = (const float4*)(nx2f + (long)t * 1024);
  float4 xv[4];
#pragma unroll
  for (int i = 0; i < 4; ++i) xv[i] = xr[l*4 + i];
  float lg[8];
#pragma unroll
  for (int e = 0; e < 8; ++e) {
    const float4* wr = (const float4*)(Wg + e * 1024);
    float s = 0.f;
#pragma unroll
    for (int i = 0; i < 4; ++i) {
      const float4 wv = wr[l*4 + i];
      s += xv[i].x*wv.x + xv[i].y*wv.y + xv[i].z*wv.z + xv[i].w*wv.w;
    }
#pragma unroll
    for (int msk = 1; msk < 64; msk <<= 1) s += __shfl_xor(s, msk);
    lg[e] = s;
  }
  float mx = lg[0];
#pragma unroll
  for (int e = 1; e < 8; ++e) mx = fmaxf(mx, lg[e]);
  float den = 0.f, pe[8];
#pragma unroll
  for (int e = 0; e < 8; ++e) { pe[e] = expf(lg[e] - mx); den += pe[e]; }
  const float invd = 1.0f / den;
  float ent = 0.f;
#pragma unroll
  for (int e = 0; e < 8; ++e) {
    const float p = pe[e] * invd;
    ent -= p * logf(fmaxf(p, 1e-6f));
  }
  int s0 = 0; float v0 = lg[0];
#pragma unroll
  for (int e = 1; e < 8; ++e) if (lg[e] > v0) { v0 = lg[e]; s0 = e; }
  int s1 = (s0 == 0) ? 1 : 0; float v1 = -INFINITY;
#pragma unroll
  for (int e = 0; e < 8; ++e) if (e != s0 && lg[e] > v1) { v1 = lg[e]; s1 = e; }
  float w0 = expf(v0 - mx) * invd;
  float w1 = expf(v1 - mx) * invd;
  const float wn = 1.0f / (w0 + w1);
  w0 *= wn; w1 *= wn;

  float myv = lg[0];
#pragma unroll
  for (int e = 1; e < 8; ++e) myv = (l == e) ? lg[e] : myv;
  if (l < 8) outLogits[t*8 + l] = myv;

  if (l == 0) {
    atomicAdd(outEnt, ent * (1.0f / 4096.0f));
    const int sl0 = atomicAdd(&cnt[s0], 1);
    tok[s0*4096 + sl0] = t;
    pidx[t*2 + 0] = s0*4096 + sl0;
    pw[t*2 + 0] = w0;
    const int sl1 = atomicAdd(&cnt[s1], 1);
    tok[s1*4096 + sl1] = t;
    pidx[t*2 + 1] = s1*4096 + sl1;
    pw[t*2 + 1] = w1;
  }
}

__global__ void init_kernel(int* cnt, float* ent) {
  const int i = threadIdx.x;
  if (i < 8) cnt[i] = 0;
  if (i == 8) *ent = 0.f;
}

__global__ void finalize_kernel(const int* __restrict__ cnt, int* __restrict__ offs) {
  if (threadIdx.x == 0) {
    int o = 0;
#pragma unroll
    for (int e = 0; e < 8; ++e) { offs[e] = o; o += cnt[e]; }
  }
}

// ---------------- MoE expert GEMMs (plain f16, routed tokens only) ----------
#define GM_FFN1 0
#define GM_FFN2 1

template<int MODE>
__global__ __launch_bounds__(256, 2) void gemm_moe_kernel(
    const f16* __restrict__ A, const f16* __restrict__ Bw,
    f16* __restrict__ C, int N, int K,
    const int* __restrict__ tok, const int* __restrict__ cnt, const int* __restrict__ offs)
{
  __shared__ __align__(16) f16 sA[128*32], sB[128*32];
  const int e = blockIdx.z;
  const int cntE = cnt[e];
  const int tm0 = blockIdx.y * 128;
  if (tm0 >= cntE) return;
  const int rowOff = offs[e];
  const f16* Bp = Bw + (long)e * N * K;
  const int tid = threadIdx.x;
  const int l = tid & 63, w = tid >> 6;
  const int wm = w >> 1, wn = w & 1;
  const int tn0 = blockIdx.x * 128;
  const int kg = l >> 4, r16 = l & 15;
  const int srow = w*32 + (l >> 2);
  const int scol = (l & 3) * 8;
  const int ldsbase = w * 1024;

  long arow[2];
#pragma unroll
  for (int i = 0; i < 2; ++i) {
    int r = tm0 + srow + i*16;
    if (r > cntE - 1) r = cntE - 1;
    arow[i] = (MODE == GM_FFN1) ? (long)tok[e*4096 + r] : (long)(rowOff + r);
  }

  f32x4 acc[4][4] = {};
  for (int k0 = 0; k0 < K; k0 += 32) {
#pragma unroll
    for (int i = 0; i < 2; ++i) {
      const int row = srow + i*16;
      const int lo = ldsbase + i*512;
      gl_lds16(A + arow[i]*K + k0 + scol, &sA[lo]);
      gl_lds16(Bp + (long)(tn0 + row)*K + k0 + scol, &sB[lo]);
    }
    __syncthreads();
    f16x8 af[4], bfr[4];
#pragma unroll
    for (int m = 0; m < 4; ++m)
      af[m] = *(const f16x8*)&sA[(wm*64 + m*16 + r16)*32 + kg*8];
#pragma unroll
    for (int n = 0; n < 4; ++n)
      bfr[n] = *(const f16x8*)&sB[(wn*64 + n*16 + r16)*32 + kg*8];
#pragma unroll
    for (int m = 0; m < 4; ++m)
#pragma unroll
      for (int n = 0; n < 4; ++n)
        acc[m][n] = MFMA16(af[m], bfr[n], acc[m][n]);
    __syncthreads();
  }

#pragma unroll
  for (int m = 0; m < 4; ++m)
#pragma unroll
    for (int n = 0; n < 4; ++n)
#pragma unroll
      for (int r = 0; r < 4; ++r) {
        const int rr = tm0 + wm*64 + m*16 + kg*4 + r;
        if (rr < cntE) {
          const int col = tn0 + wn*64 + n*16 + r16;
          float v = acc[m][n][r];
          if (MODE == GM_FFN1) v = 0.5f * v * (1.0f + erff(v * 0.70710678118654752f));
          C[(long)(rowOff + rr) * N + col] = (f16)v;
        }
      }
}

// ---------------- final combine ----------------
__global__ __launch_bounds__(256) void combine_kernel(
    const float* __restrict__ x2, const f16* __restrict__ eo,
    const int* __restrict__ pidx, const float* __restrict__ pw,
    const int* __restrict__ offs, const float* __restrict__ rsp,
    float* __restrict__ out)
{
  const int t = blockIdx.x;
  const int tid = threadIdx.x;
  const int i0 = pidx[t*2], i1 = pidx[t*2 + 1];
  const float w0 = pw[t*2], w1 = pw[t*2 + 1];
  const long r0 = (long)offs[i0 >> 12] + (i0 & 4095);
  const long r1 = (long)offs[i1 >> 12] + (i1 & 4095);
  const float rs = rsp[0];
  const float4 xv = ((const float4*)(x2 + (long)t*1024))[tid];
  const f16x4 e0 = *(const f16x4*)(eo + r0*1024 + tid*4);
  const f16x4 e1 = *(const f16x4*)(eo + r1*1024 + tid*4);
  float4 o;
  o.x = xv.x + rs * (w0*(float)e0[0] + w1*(float)e1[0]);
  o.y = xv.y + rs * (w0*(float)e0[1] + w1*(float)e1[1]);
  o.z = xv.z + rs * (w0*(float)e0[2] + w1*(float)e1[2]);
  o.w = xv.w + rs * (w0*(float)e0[3] + w1*(float)e1[3]);
  ((float4*)(out + (long)t*1024))[tid] = o;
}

// ---------------------------------------------------------------------------
extern "C" void kernel_launch(void* const* d_in, const int* in_sizes, int n_in,
                              void* d_out, int out_size, void* d_ws, size_t ws_size,
                              hipStream_t stream)
{
  const float* x    = (const float*)d_in[0];
  const float* Wqkv = (const float*)d_in[1];
  const float* Wo   = (const float*)d_in[2];
  const float* ln1g = (const float*)d_in[3];
  const float* ln1b = (const float*)d_in[4];
  const float* ln2g = (const float*)d_in[5];
  const float* ln2b = (const float*)d_in[6];
  const float* Wg   = (const float*)d_in[7];
  const float* W1   = (const float*)d_in[8];
  const float* W2   = (const float*)d_in[9];
  const float* rsp  = (const float*)d_in[10];
  float* out = (float*)d_out;

  char* p = (char*)d_ws;
  auto alloc = [&](size_t n) { char* r = p; p += (n + 255) & ~(size_t)255; return r; };
  f16*   wqh  = (f16*)alloc(3072L*1024*2);
  f16*   wql  = (f16*)alloc(3072L*1024*2);
  f16*   woh  = (f16*)alloc(1024L*1024*2);
  f16*   wol  = (f16*)alloc(1024L*1024*2);
  f16*   w1h  = (f16*)alloc(8L*2048*1024*2);
  f16*   w2h  = (f16*)alloc(8L*1024*2048*2);
  f16*   nxh  = (f16*)alloc(4096L*1024*2);
  f16*   nxl  = (f16*)alloc(4096L*1024*2);
  f16*   qkh  = (f16*)alloc(4096L*3072*2);
  f16*   qkl  = (f16*)alloc(4096L*3072*2);
  f16*   ctxh = (f16*)alloc(4096L*1024*2);
  f16*   ctxl = (f16*)alloc(4096L*1024*2);
  float* x2   = (float*)alloc(4096L*1024*4);
  f16*   nx2h = (f16*)alloc(4096L*1024*2);
  float* nx2f = (float*)alloc(4096L*1024*4);
  int*   cnt  = (int*)alloc(256);
  int*   offs = (int*)alloc(256);
  int*   tok  = (int*)alloc(8L*4096*4);
  int*   pidx = (int*)alloc(4096L*2*4);
  float* pw   = (float*)alloc(4096L*2*4);
  if ((size_t)(p - (char*)d_ws) > ws_size) return;
  // aliases (lifetimes disjoint):
  f16* hbuf = qkh;            // FFN hidden over qkv (dead after attn)
  f16* eob  = nxh;            // expert out over nx (dead after QKV gemm)
  f16* vTh  = (f16*)nx2f;     // V^T over nx2f (nx2f written at LN2, after attn)
  f16* vTl  = vTh + 4096L*1024;

  // 1) weight conversion
  cvt_w_kernel<<<3072*1024/4/256, 256, 0, stream>>>(Wqkv, wqh, wql, 3072*1024/4);
  cvt_w_kernel<<<1024*1024/4/256, 256, 0, stream>>>(Wo, woh, wol, 1024*1024/4);
  cvt_h_kernel<<<8*2048*1024/4/256, 256, 0, stream>>>(W1, w1h, 8*2048*1024/4);
  cvt_h_kernel<<<8*1024*2048/4/256, 256, 0, stream>>>(W2, w2h, 8*1024*2048/4);
  // 2) LN1 -> split nx
  ln_kernel<<<4096, 256, 0, stream>>>(x, ln1g, ln1b, nxh, nxl, nullptr, nullptr);
  // 3) QKV projection (split)
  gemm_split_kernel<GM_QKV><<<dim3(24, 32), 256, 0, stream>>>(
      nxh, nxl, wqh, wql, qkh, qkl, nullptr, nullptr, nullptr, 3072, 1024);
  // 4) V transpose, then flash attention
  vt_kernel<<<dim3(64, 16), 256, 0, stream>>>(qkh, qkl, vTh, vTl);
  attn_kernel<<<dim3(64, 16), 256, 0, stream>>>(qkh, qkl, vTh, vTl, ctxh, ctxl);
  // 5) Wo projection + residual -> x2
  gemm_split_kernel<GM_WO><<<dim3(8, 32), 256, 0, stream>>>(
      ctxh, ctxl, woh, wol, nullptr, nullptr, x2, x, rsp, 1024, 1024);
  // 6) LN2 -> f16 (MoE) + fp32 (router)
  ln_kernel<<<4096, 256, 0, stream>>>(x2, ln2g, ln2b, nullptr, nullptr, nx2h, nx2f);
  // 7) routing
  init_kernel<<<1, 64, 0, stream>>>(cnt, out + 4227072);
  router_kernel<<<1024, 256, 0, stream>>>(nx2f, Wg, out + 4194304, out + 4227072,
                                          cnt, tok, pidx, pw);
  finalize_kernel<<<1, 64, 0, stream>>>(cnt, offs);
  // 8) expert FFN (routed tokens only)
  gemm_moe_kernel<GM_FFN1><<<dim3(16, 32, 8), 256, 0, stream>>>(
      nx2h, w1h, hbuf, 2048, 1024, tok, cnt, offs);
  gemm_moe_kernel<GM_FFN2><<<dim3(8, 32, 8), 256, 0, stream>>>(
      hbuf, w2h, eob, 1024, 2048, tok, cnt, offs);
  // 9) combine + residual -> out
  combine_kernel<<<4096, 256, 0, stream>>>(x2, eob, pidx, pw, offs, rsp, out);
}